// Round 2
// baseline (1445.601 us; speedup 1.0000x reference)
//
#include <hip/hip_runtime.h>

// Problem constants
#define B_SZ 512
#define T_SZ 512
#define I_SZ 256
#define H_SZ 250

typedef __bf16 bf16x8 __attribute__((ext_vector_type(8)));
typedef float  f32x4  __attribute__((ext_vector_type(4)));

__device__ __forceinline__ float fast_tanh(float x) {
    float ax = __builtin_fabsf(x);
    float e  = __expf(-2.0f * ax);          // v_exp_f32 path
    float r  = (1.0f - e) / (1.0f + e);
    return __builtin_copysignf(r, x);
}

// Workgroup barrier that drains ONLY lgkmcnt (LDS) — leaves global loads and
// stores in flight. Safe here: the only cross-wave dependency through the
// barrier is the LDS h-buffer handoff; global stores are never read by other
// waves in the block, and global loads are consumed by the issuing wave with
// compiler-inserted vmcnt waits before use.
__device__ __forceinline__ void barrier_lgkm() {
    asm volatile("s_waitcnt lgkmcnt(0)\n\ts_barrier" ::: "memory");
}

__device__ __forceinline__ bf16x8 cvt8(const float4 lo, const float4 hi) {
    bf16x8 r;
    r[0] = (__bf16)lo.x; r[1] = (__bf16)lo.y; r[2] = (__bf16)lo.z; r[3] = (__bf16)lo.w;
    r[4] = (__bf16)hi.x; r[5] = (__bf16)hi.y; r[6] = (__bf16)hi.z; r[7] = (__bf16)hi.w;
    return r;
}

// ---------------------------------------------------------------------------
// Kernel 1: xproj[m][j] = x[m][:] . Wx[j][:] + bh[j]  (m = b*T+t), into out.
// Barrier-free, LDS-free: fragments built straight from global (x streamed
// from HBM, Wx is 256 KB -> L2-resident). BM=64 rows/block, BN=256 (all of
// N=250 padded) so x is read exactly once. 4096 blocks x 256 thr.
// ---------------------------------------------------------------------------
__global__ __launch_bounds__(256, 2) void xproj_kernel(
    const float* __restrict__ x,    // [M][256], M = B*T
    const float* __restrict__ Wx,   // [250][256]
    const float* __restrict__ bh,   // [250]
    float* __restrict__ out)        // [M][250]
{
    const int m0   = blockIdx.x * 64;
    const int tid  = threadIdx.x;
    const int lane = tid & 63;
    const int wave = tid >> 6;      // wave owns cols n0..n0+63
    const int l15  = lane & 15;
    const int quad = lane >> 4;
    const int n0   = wave * 64;

    f32x4 acc[4][4];                // [tm][tl]
#pragma unroll
    for (int i = 0; i < 4; ++i)
#pragma unroll
        for (int j = 0; j < 4; ++j)
            acc[i][j] = (f32x4){0.f, 0.f, 0.f, 0.f};

    // A rows: x[m0 + tm*16 + l15][quad*8 + ...]
    const float* arow[4];
#pragma unroll
    for (int tm = 0; tm < 4; ++tm)
        arow[tm] = x + (size_t)(m0 + tm * 16 + l15) * I_SZ + quad * 8;

    // B rows: Wx[n0 + tl*16 + l15][quad*8 + ...]; clamp OOB rows to row 0
    // (garbage values only pollute discarded columns gn >= 250).
    const float* brow[4];
#pragma unroll
    for (int tl = 0; tl < 4; ++tl) {
        int gn = n0 + tl * 16 + l15;
        brow[tl] = Wx + (size_t)(gn < H_SZ ? gn : 0) * I_SZ + quad * 8;
    }

#pragma unroll
    for (int kk = 0; kk < I_SZ / 32; ++kk) {
        bf16x8 af[4], bfr[4];
#pragma unroll
        for (int tm = 0; tm < 4; ++tm) {
            const float4 lo = *(const float4*)(arow[tm] + kk * 32);
            const float4 hi = *(const float4*)(arow[tm] + kk * 32 + 4);
            af[tm] = cvt8(lo, hi);
        }
#pragma unroll
        for (int tl = 0; tl < 4; ++tl) {
            const float4 lo = *(const float4*)(brow[tl] + kk * 32);
            const float4 hi = *(const float4*)(brow[tl] + kk * 32 + 4);
            bfr[tl] = cvt8(lo, hi);
        }
#pragma unroll
        for (int tm = 0; tm < 4; ++tm)
#pragma unroll
            for (int tl = 0; tl < 4; ++tl)
                acc[tm][tl] = __builtin_amdgcn_mfma_f32_16x16x32_bf16(af[tm], bfr[tl], acc[tm][tl], 0, 0, 0);
    }

    // epilogue: C row(m) = quad*4+reg, col(n) = lane&15
#pragma unroll
    for (int tl = 0; tl < 4; ++tl) {
        int gn = n0 + tl * 16 + l15;
        if (gn < H_SZ) {
            float bias = bh[gn];
#pragma unroll
            for (int tm = 0; tm < 4; ++tm) {
#pragma unroll
                for (int r = 0; r < 4; ++r) {
                    int gm = m0 + tm * 16 + quad * 4 + r;
                    out[(size_t)gm * H_SZ + gn] = acc[tm][tl][r] + bias;
                }
            }
        }
    }
}

// ---------------------------------------------------------------------------
// Kernel 2: recurrence. 256 blocks x 2 batch rows, 1 block/CU.
// Wh in register B-fragments; h ping-pong in LDS; xproj prefetched 4 steps
// ahead in registers; lgkm-only barriers keep global traffic off the
// critical path.
// ---------------------------------------------------------------------------
#define HLD 264   // LDS row stride for h (bf16)

__global__ __launch_bounds__(256, 1) void rnn_kernel(
    const float* __restrict__ h0,   // [B][250]
    const float* __restrict__ Wh,   // [250][250]
    float* __restrict__ out)        // [B][T][250], pre-filled with xproj+bias
{
    __shared__ __align__(16) __bf16 hbuf[2][16 * HLD];

    const int b0   = blockIdx.x * 2;
    const int tid  = threadIdx.x;
    const int lane = tid & 63;
    const int wave = tid >> 6;
    const int l15  = lane & 15;
    const int quad = lane >> 4;
    const int j0w  = wave * 64;

    // zero both h buffers (rows 2..15 and cols >=250 stay 0 forever)
    for (int i = tid; i < 2 * 16 * HLD; i += 256)
        ((__bf16*)hbuf)[i] = (__bf16)0.f;
    __syncthreads();

    for (int k = tid; k < H_SZ; k += 256) {
        hbuf[0][0 * HLD + k] = (__bf16)h0[(size_t)(b0 + 0) * H_SZ + k];
        hbuf[0][1 * HLD + k] = (__bf16)h0[(size_t)(b0 + 1) * H_SZ + k];
    }

    // Wh fragments: B[n = lane&15][k = quad*8 + e]
    bf16x8 wf[4][8];
#pragma unroll
    for (int tl = 0; tl < 4; ++tl) {
        int j = j0w + tl * 16 + l15;
#pragma unroll
        for (int kt = 0; kt < 8; ++kt) {
            int kb = kt * 32 + quad * 8;
            bf16x8 v;
#pragma unroll
            for (int e = 0; e < 8; ++e) {
                int k = kb + e;
                v[e] = (j < H_SZ && k < H_SZ) ? (__bf16)Wh[(size_t)j * H_SZ + k] : (__bf16)0.f;
            }
            wf[tl][kt] = v;
        }
    }
    __syncthreads();

    float* o0 = out + (size_t)(b0 + 0) * T_SZ * H_SZ;
    float* o1 = out + (size_t)(b0 + 1) * T_SZ * H_SZ;

    int  jc[4];
    bool jv[4];
#pragma unroll
    for (int tl = 0; tl < 4; ++tl) {
        jc[tl] = j0w + tl * 16 + l15;
        jv[tl] = (quad == 0) && (jc[tl] < H_SZ);
    }

    // xproj register pipeline, depth 4 (lead ~4 steps > HBM latency)
    float xa[4][4], xb[4][4];   // [pipe][tl]
#pragma unroll
    for (int p = 0; p < 4; ++p) {
#pragma unroll
        for (int tl = 0; tl < 4; ++tl) {
            xa[p][tl] = jv[tl] ? o0[(size_t)p * H_SZ + jc[tl]] : 0.f;
            xb[p][tl] = jv[tl] ? o1[(size_t)p * H_SZ + jc[tl]] : 0.f;
        }
    }

    for (int tt = 0; tt < T_SZ; tt += 4) {
#pragma unroll
        for (int u = 0; u < 4; ++u) {
            const int t   = tt + u;
            const int cur = t & 1;
            const int nxt = cur ^ 1;

            barrier_lgkm();   // hbuf[cur] ready; loads/stores stay in flight

            bf16x8 af[8];
#pragma unroll
            for (int kt = 0; kt < 8; ++kt)
                af[kt] = *(const bf16x8*)&hbuf[cur][l15 * HLD + kt * 32 + quad * 8];

#pragma unroll
            for (int tl = 0; tl < 4; ++tl) {
                f32x4 acc = (f32x4){0.f, 0.f, 0.f, 0.f};
#pragma unroll
                for (int kt = 0; kt < 8; ++kt)
                    acc = __builtin_amdgcn_mfma_f32_16x16x32_bf16(af[kt], wf[tl][kt], acc, 0, 0, 0);

                if (jv[tl]) {
                    float v0 = fast_tanh(acc[0] + xa[u][tl]);
                    float v1 = fast_tanh(acc[1] + xb[u][tl]);
                    o0[(size_t)t * H_SZ + jc[tl]] = v0;
                    o1[(size_t)t * H_SZ + jc[tl]] = v1;
                    hbuf[nxt][0 * HLD + jc[tl]] = (__bf16)v0;
                    hbuf[nxt][1 * HLD + jc[tl]] = (__bf16)v1;
                }
            }

            // prefetch step t+4 into slot u
            const int tp = t + 4;
            if (tp < T_SZ) {
#pragma unroll
                for (int tl = 0; tl < 4; ++tl) {
                    xa[u][tl] = jv[tl] ? o0[(size_t)tp * H_SZ + jc[tl]] : 0.f;
                    xb[u][tl] = jv[tl] ? o1[(size_t)tp * H_SZ + jc[tl]] : 0.f;
                }
            }
        }
    }
}

extern "C" void kernel_launch(void* const* d_in, const int* in_sizes, int n_in,
                              void* d_out, int out_size, void* d_ws, size_t ws_size,
                              hipStream_t stream) {
    const float* x  = (const float*)d_in[0];
    const float* h  = (const float*)d_in[1];
    const float* Wx = (const float*)d_in[2];
    const float* Wh = (const float*)d_in[3];
    const float* bh = (const float*)d_in[4];
    float* out = (float*)d_out;

    const int M = B_SZ * T_SZ;                 // 262144
    xproj_kernel<<<dim3(M / 64), dim3(256), 0, stream>>>(x, Wx, bh, out);
    rnn_kernel<<<dim3(B_SZ / 2), dim3(256), 0, stream>>>(h, Wh, out);
}